// Round 8
// baseline (171.098 us; speedup 1.0000x reference)
//
#include <hip/hip_runtime.h>
#include <math.h>
#include <stdint.h>

#define EPS     1e-7f
#define NR      8192
#define DX      256             // also bytes per fp8 row
#define DZ      64
#define KNN     5
#define KEEP    6               // per-split kept candidates (packed u32)
#define NSPLIT  8
#define NPOOL   (NSPLIT * KEEP) // 48
#define NCAND   16              // exact-recompute pool in finalize
#define JS      (NR / NSPLIT)   // 1024
#define JT      32              // j-cols consumed per chunk (reg-streamed, no LDS)
#define NCHUNK  (JS / 2 / JT)   // 16 (each wave owns a 512-col half-split)
#define RBLK    64              // i-rows per block
#define SC1     0x7F7F7F7F     // E8M0 scales = 1.0 in every byte (opsel-proof)
#define BIASF   256.0f          // C-seed bias: acc = dot - sqj/2 - 256 < 0 always (24 sigma)

typedef float  f32x4 __attribute__((ext_vector_type(4)));
typedef int    i32x8 __attribute__((ext_vector_type(8)));

// guaranteed v_min_u32/v_max_u32 (ternary select can compile to v_cmp+v_cndmask = 2 ops)
__device__ __forceinline__ uint32_t umin_(uint32_t a, uint32_t b) {
    return __builtin_elementwise_min(a, b);
}
__device__ __forceinline__ uint32_t umax_(uint32_t a, uint32_t b) {
    return __builtin_elementwise_max(a, b);
}

// float -> OCP e4m3fn, round-nearest (ties-away; bias irrelevant at this noise level)
__device__ __forceinline__ uint32_t to_e4m3(float f) {
    const uint32_t u = __float_as_uint(f);
    const uint32_t s = (u >> 24) & 0x80u;
    const int e = (int)((u >> 23) & 0xFFu) - 127;
    if (e < -10) return s;                         // underflow to +/-0
    if (e > 8)   return s | 0x7Eu;                 // clamp to 448 (never for N(0,1))
    const uint32_t mant = (u & 0x7FFFFFu) | 0x800000u;
    const int shift = (e < -6) ? (14 - e) : 20;    // subnormal: extra shift
    uint32_t q = (mant + (1u << (shift - 1))) >> shift;
    int E = (e < -6) ? 0 : (e + 7);
    if (q >= 16) { q >>= 1; E += 1; }              // normal rounding carry
    if (E == 0) return s | q;                      // q==8 encodes E=1,m=0 naturally
    return s | ((uint32_t)E << 3) | (q & 7u);
}

// ------------------------------------------------- X -> fp8 + row sq-sums (+ zero out)
__global__ __launch_bounds__(256) void split_k(const float* __restrict__ X,
                                               uint8_t* __restrict__ Xq,
                                               float* __restrict__ sqX,
                                               float* __restrict__ out) {
    if (blockIdx.x == 0 && threadIdx.x == 0) out[0] = 0.0f;  // finalize runs later on stream
    const int row  = blockIdx.x * 4 + (threadIdx.x >> 6);
    const int lane = threadIdx.x & 63;
    const float4 v = *(const float4*)&X[(size_t)row * DX + lane * 4];
    float s = v.x * v.x + v.y * v.y + v.z * v.z + v.w * v.w;
    const uint32_t b = to_e4m3(v.x) | (to_e4m3(v.y) << 8) |
                       (to_e4m3(v.z) << 16) | (to_e4m3(v.w) << 24);
    ((uint32_t*)Xq)[(size_t)row * (DX / 4) + lane] = b;
    #pragma unroll
    for (int o = 32; o > 0; o >>= 1) s += __shfl_down(s, o);
    if (lane == 0) sqX[row] = s;
}

// ------------------------------------------------- MX-fp8 K=128 MFMA + top-k, BARRIER-FREE
// R6 POST-MORTEM: occupancy 22->35% (VGPR 44) yet wall IDENTICAL 45.6us. The invariant
// across 2-barrier/dbuf/4-wave/8-wave is the lockstep barrier-chunk convoy: 16x per block
// all waves park at __syncthreads+vmcnt(0) -- extra waves just park too. No pipe sums to
// 45.5 (MFMA ~7, fold ~7, LDS 10-20, DMA ~3). This revision DELETES the mechanism:
//  * Xq (2MB) is L2-resident (256KB/split/XCD, split pinned via blockIdx&7). B fragments
//    stream L2->registers (8 global_load_dwordx4 per 32-col chunk). NO staging LDS, NO
//    main-loop barriers. Waves run free; compiler software-pipelines next-chunk loads
//    under the fold (reg budget 256). L2 traffic ~0.5GB = ~1.4 TB/s/XCD (ceiling 4.3).
//  * A and B both read the PLAIN Xq layout -> same lane->k permutation on both operands
//    -> dot invariant (self-cancelling, as before).
//  * per-wave epilogue emits sorted-6 (stage1 (4,4)->6, butterfly (6,6)->6) so the
//    cross-wave merge + KEEP=6 pool semantics are bit-identical to prior rounds. Only
//    LDS: 3KB mb2 + ONE barrier at kernel end.
// (R7 infra-failed with no dispatch; audit found no hang/OOB/misalignment -- resubmit.)
// Fold (unchanged): per-lane sorted-4, (2,4) rank-merge, min3-shaped. Sorted-4 safe:
// dropping a true top-5 neighbor needs 5-of-5 in one 32-cand lane-stream:
// P=(1/256)^4/row -> 2e-6 over 8192 rows.
// Key is a per-row monotone transform of d2 (C-seeded with -sqj/2-256; all-negative ->
// uint-monotone) -> selection unchanged; finalize re-ranks exactly in fp32.
// CORRECTNESS/PERF NOTES (hard-won):
//  * NO runtime subscripts into register arrays (R5: 711 MB scratch). Constant-index only.
//  * NO branches in the fold (R2: exec-guard serialized the ILP networks, always taken).
#define FOLD_BODY(KILL)                                                                   \
    _Pragma("unroll")                                                                     \
    for (int g = 0; g < 2; ++g) {                                                         \
        _Pragma("unroll")                                                                 \
        for (int r = 0; r < 4; ++r) {                                                     \
            const int q = g * 4 + r;                                                      \
            uint32_t c0 = (__float_as_uint(acc[0][g][r]) & 0xFFFFE000u) | (uint32_t)j0;   \
            uint32_t c1 = (__float_as_uint(acc[1][g][r]) & 0xFFFFE000u) | (uint32_t)j1;   \
            if (KILL) {                                                                   \
                const int irow = rowbase + g * 16 + quad * 4 + r;                         \
                c0 = (j0 == irow) ? 0xFFFFFFFFu : c0;                                     \
                c1 = (j1 == irow) ? 0xFFFFFFFFu : c1;                                     \
            }                                                                             \
            const uint32_t lo = umin_(c0, c1);                                            \
            const uint32_t hi = umax_(c0, c1);                                            \
            const uint32_t b0 = best[q][0], b1 = best[q][1], b2 = best[q][2],             \
                           b3 = best[q][3];                                               \
            best[q][0] = umin_(b0, lo);                                                   \
            best[q][1] = umin_(umin_(b1, hi), umax_(b0, lo));                             \
            best[q][2] = umin_(umin_(b2, umax_(b1, lo)), umax_(b0, hi));                  \
            best[q][3] = umin_(umin_(b3, umax_(b2, lo)), umax_(b1, hi));                  \
        }                                                                                 \
    }

__global__ __launch_bounds__(256, 2) void mfma_topk_k(const uint8_t* __restrict__ Xq,
                                                      const float* __restrict__ sqX,
                                                      uint32_t* __restrict__ partials) {
    __shared__ uint32_t mb2[RBLK][2][KEEP];            // ONLY LDS (3 KB)

    const int tid  = threadIdx.x;
    const int w    = tid >> 6;                         // 0..3
    const int lane = tid & 63;
    const int n    = lane & 15;
    const int quad = lane >> 4;
    const int h    = w >> 1;                           // rowgroup (32 rows)
    const int sp   = w & 1;                            // col half (512 of 1024)
    const int s    = blockIdx.x & 7;                   // split (XCD round-robin)
    const int ib   = (blockIdx.x >> 3) * RBLK;
    const int jb0  = s * JS + sp * (JS / 2);           // this wave's 512-col window
    const int rowbase = ib + h * 32;

    // diagonal lives in exactly one chunk per wave (or none); scalar-branch key
    const int rel   = rowbase - jb0;
    const int cdiag = __builtin_amdgcn_readfirstlane(
                          (rel >= 0 && rel < JS / 2) ? (rel >> 5) : -1);

    // A fragments: 2 rowgroups x 2 K-halves of 128 (32 B = i32x8 each; 32 VGPR total)
    i32x8 Aq[2][2];
    #pragma unroll
    for (int g = 0; g < 2; ++g)
        #pragma unroll
        for (int kf = 0; kf < 2; ++kf)
            Aq[g][kf] = *(const i32x8*)(Xq + (size_t)(rowbase + g * 16 + n) * DX
                                        + kf * 128 + quad * 32);

    uint32_t best[8][4];     // q = g*4+r; ascending sorted-4; compile-time indices only
    #pragma unroll
    for (int q = 0; q < 8; ++q)
        #pragma unroll
        for (int k = 0; k < 4; ++k) best[q][k] = 0xFFFFFFFFu;

    // per-lane streaming pointers (advance 32 cols = 8 KB per chunk)
    const uint8_t* bp0 = Xq + (size_t)(jb0 + n) * DX + quad * 32;        // si=0 col
    const uint8_t* bp1 = bp0 + 16 * DX;                                  // si=1 col
    const float*   sqp = sqX + jb0 + n;
    int j0 = jb0 + n;                                  // si=0 col index; j1 = j0+16

    for (int jc = 0; jc < NCHUNK; ++jc) {
        // 8 direct L2->reg loads (compiler pipelines across iterations; no barriers)
        const uint4 b00 = *(const uint4*)(bp0);
        const uint4 b01 = *(const uint4*)(bp0 + 16);
        const uint4 b02 = *(const uint4*)(bp0 + 128);
        const uint4 b03 = *(const uint4*)(bp0 + 144);
        const uint4 b10 = *(const uint4*)(bp1);
        const uint4 b11 = *(const uint4*)(bp1 + 16);
        const uint4 b12 = *(const uint4*)(bp1 + 128);
        const uint4 b13 = *(const uint4*)(bp1 + 144);

        // C-seed: acc starts at -sqj/2 - 256 so final acc bits are the ranking key
        const float ini0 = fmaf(-0.5f, sqp[0],  -BIASF);
        const float ini1 = fmaf(-0.5f, sqp[16], -BIASF);

        f32x4 acc[2][2];  // [si][g]
        #pragma unroll
        for (int r = 0; r < 4; ++r) {
            acc[0][0][r] = ini0; acc[0][1][r] = ini0;
            acc[1][0][r] = ini1; acc[1][1][r] = ini1;
        }

        union U { uint4 p[2]; i32x8 v; } u;
        u.p[0] = b00; u.p[1] = b01;   // si=0, kf=0
        acc[0][0] = __builtin_amdgcn_mfma_scale_f32_16x16x128_f8f6f4(
                        Aq[0][0], u.v, acc[0][0], 0, 0, 0, SC1, 0, SC1);
        acc[0][1] = __builtin_amdgcn_mfma_scale_f32_16x16x128_f8f6f4(
                        Aq[1][0], u.v, acc[0][1], 0, 0, 0, SC1, 0, SC1);
        u.p[0] = b02; u.p[1] = b03;   // si=0, kf=1
        acc[0][0] = __builtin_amdgcn_mfma_scale_f32_16x16x128_f8f6f4(
                        Aq[0][1], u.v, acc[0][0], 0, 0, 0, SC1, 0, SC1);
        acc[0][1] = __builtin_amdgcn_mfma_scale_f32_16x16x128_f8f6f4(
                        Aq[1][1], u.v, acc[0][1], 0, 0, 0, SC1, 0, SC1);
        u.p[0] = b10; u.p[1] = b11;   // si=1, kf=0
        acc[1][0] = __builtin_amdgcn_mfma_scale_f32_16x16x128_f8f6f4(
                        Aq[0][0], u.v, acc[1][0], 0, 0, 0, SC1, 0, SC1);
        acc[1][1] = __builtin_amdgcn_mfma_scale_f32_16x16x128_f8f6f4(
                        Aq[1][0], u.v, acc[1][1], 0, 0, 0, SC1, 0, SC1);
        u.p[0] = b12; u.p[1] = b13;   // si=1, kf=1
        acc[1][0] = __builtin_amdgcn_mfma_scale_f32_16x16x128_f8f6f4(
                        Aq[0][1], u.v, acc[1][0], 0, 0, 0, SC1, 0, SC1);
        acc[1][1] = __builtin_amdgcn_mfma_scale_f32_16x16x128_f8f6f4(
                        Aq[1][1], u.v, acc[1][1], 0, 0, 0, SC1, 0, SC1);

        // fold 16 candidates/lane as 8 sorted-pairs merged into sorted-4
        // (C layout: col=n, row=quad*4+r; key = acc bits, all-negative -> uint-monotone)
        const int j1 = j0 + 16;
        if (jc != cdiag) {
            FOLD_BODY(0)
        } else {
            FOLD_BODY(1)
        }
        bp0 += JT * DX; bp1 += JT * DX; sqp += JT; j0 += JT;
    }

    // per-q: stage 1 merges sorted-4 pairs -> sorted-6, stages 2-4 butterfly (6,6)->6,
    // then LDS dump (capacity 6 per half-split -> pool semantics identical to KEEP=6).
    #pragma unroll
    for (int q = 0; q < 8; ++q) {
        const uint32_t s0 = best[q][0], s1 = best[q][1], s2 = best[q][2], s3 = best[q][3];
        const uint32_t t0 = __shfl_xor(s0, 1);
        const uint32_t t1 = __shfl_xor(s1, 1);
        const uint32_t t2 = __shfl_xor(s2, 1);
        const uint32_t t3 = __shfl_xor(s3, 1);
        // (4,4) -> sorted-6
        uint32_t a0 = umin_(s0, t0);
        uint32_t a1 = umin_(umin_(s1, t1), umax_(s0, t0));
        uint32_t a2 = umin_(umin_(s2, t2), umin_(umax_(s1, t0), umax_(s0, t1)));
        uint32_t a3 = umin_(umin_(s3, t3),
                            umin_(umax_(s2, t0), umin_(umax_(s1, t1), umax_(s0, t2))));
        uint32_t a4 = umin_(umin_(umax_(s3, t0), umax_(s2, t1)),
                            umin_(umax_(s1, t2), umax_(s0, t3)));
        uint32_t a5 = umin_(umax_(s3, t1), umin_(umax_(s2, t2), umax_(s1, t3)));
        #pragma unroll
        for (int mask = 2; mask <= 8; mask <<= 1) {
            const uint32_t b0 = __shfl_xor(a0, mask);
            const uint32_t b1 = __shfl_xor(a1, mask);
            const uint32_t b2 = __shfl_xor(a2, mask);
            const uint32_t b3 = __shfl_xor(a3, mask);
            const uint32_t b4 = __shfl_xor(a4, mask);
            const uint32_t b5 = __shfl_xor(a5, mask);
            const uint32_t c0 = umin_(a0, b0);
            const uint32_t c1 = umin_(umin_(a1, b1), umax_(a0, b0));
            const uint32_t c2 = umin_(umin_(a2, b2), umin_(umax_(a1, b0), umax_(a0, b1)));
            const uint32_t c3 = umin_(umin_(a3, b3),
                                      umin_(umax_(a2, b0), umin_(umax_(a1, b1), umax_(a0, b2))));
            const uint32_t c4 = umin_(umin_(a4, b4),
                                      umin_(umin_(umax_(a3, b0), umax_(a2, b1)),
                                            umin_(umax_(a1, b2), umax_(a0, b3))));
            const uint32_t c5 = umin_(umin_(a5, b5),
                                      umin_(umin_(umax_(a4, b0), umax_(a3, b1)),
                                            umin_(umax_(a2, b2),
                                                  umin_(umax_(a1, b3), umax_(a0, b4)))));
            a0 = c0; a1 = c1; a2 = c2; a3 = c3; a4 = c4; a5 = c5;
        }
        const int rloc = h * 32 + (q >> 2) * 16 + quad * 4 + (q & 3);
        uint32_t v = a0;                 // lane n emits element n via constant select chain
        v = (n == 1) ? a1 : v;
        v = (n == 2) ? a2 : v;
        v = (n == 3) ? a3 : v;
        v = (n == 4) ? a4 : v;
        v = (n == 5) ? a5 : v;
        if (n < KEEP) mb2[rloc][sp][n] = v;
    }
    __syncthreads();                                   // the ONLY barrier

    // cross-wave (sp) merge of two sorted-6; emit KEEP=6 per row per split
    if (tid < RBLK) {
        const uint32_t a0 = mb2[tid][0][0], a1 = mb2[tid][0][1], a2 = mb2[tid][0][2],
                       a3 = mb2[tid][0][3], a4 = mb2[tid][0][4], a5 = mb2[tid][0][5];
        const uint32_t b0 = mb2[tid][1][0], b1 = mb2[tid][1][1], b2 = mb2[tid][1][2],
                       b3 = mb2[tid][1][3], b4 = mb2[tid][1][4], b5 = mb2[tid][1][5];
        uint32_t o[KEEP];
        o[0] = umin_(a0, b0);
        o[1] = umin_(umin_(a1, b1), umax_(a0, b0));
        o[2] = umin_(umin_(a2, b2), umin_(umax_(a1, b0), umax_(a0, b1)));
        o[3] = umin_(umin_(a3, b3), umin_(umax_(a2, b0), umin_(umax_(a1, b1), umax_(a0, b2))));
        o[4] = umin_(umin_(a4, b4), umin_(umin_(umax_(a3, b0), umax_(a2, b1)),
                                          umin_(umax_(a1, b2), umax_(a0, b3))));
        o[5] = umin_(umin_(a5, b5), umin_(umin_(umax_(a4, b0), umax_(a3, b1)),
                                          umin_(umax_(a2, b2),
                                                umin_(umax_(a1, b3), umax_(a0, b4)))));
        #pragma unroll
        for (int k = 0; k < KEEP; ++k)
            partials[(size_t)(ib + tid) * NPOOL + s * KEEP + k] = o[k];
    }
}

// ------------------------------------------------- one wave per row, ROW-COALESCED re-rank:
// bitonic-64 approx sort of the 48-pool; per candidate, all 64 lanes read its X row
// (coalesced); butterfly-reduced exact fp32 dots; bitonic-16 exact (d2,j) sort; lid; loss.
__global__ __launch_bounds__(256) void finalize_k(const uint32_t* __restrict__ parts,
                                                  const float* __restrict__ X,
                                                  const float* __restrict__ Z,
                                                  const float* __restrict__ sqX,
                                                  float* __restrict__ out) {
    __shared__ float wsum[4];
    const int wv   = threadIdx.x >> 6;
    const int lane = threadIdx.x & 63;
    const int i    = blockIdx.x * 4 + wv;

    // bitonic sort the pool across lanes (keys distinct: disjoint j; inert lanes = FFFF)
    uint32_t v = (lane < NPOOL) ? parts[(size_t)i * NPOOL + lane] : 0xFFFFFFFFu;
    #pragma unroll
    for (int kk = 2; kk <= 64; kk <<= 1) {
        #pragma unroll
        for (int jj = kk >> 1; jj > 0; jj >>= 1) {
            const uint32_t o = __shfl_xor(v, jj);
            const bool keepmin = ((lane & kk) == 0) == ((lane & jj) == 0);
            v = keepmin ? umin_(v, o) : umax_(v, o);
        }
    }
    // lanes 0..15 hold the approx top-16 ascending

    const float4 xi = *(const float4*)(X + (size_t)i * DX + lane * 4);

    float p[16];
    #pragma unroll
    for (int c = 0; c < NCAND; ++c) {
        const int jc = (int)(__shfl(v, c) & 0x1FFFu);
        const float4 xj = *(const float4*)(X + (size_t)jc * DX + lane * 4);
        p[c] = fmaf(xi.x, xj.x, fmaf(xi.y, xj.y, fmaf(xi.z, xj.z, xi.w * xj.w)));
    }
    #pragma unroll
    for (int c = 0; c < NCAND; ++c) {
        p[c] += __shfl_xor(p[c], 1);
        p[c] += __shfl_xor(p[c], 2);
        p[c] += __shfl_xor(p[c], 4);
        p[c] += __shfl_xor(p[c], 8);
    }
    const int cs = lane & 15;
    float dotv = p[0];
    dotv = (cs == 1)  ? p[1]  : dotv;
    dotv = (cs == 2)  ? p[2]  : dotv;
    dotv = (cs == 3)  ? p[3]  : dotv;
    dotv = (cs == 4)  ? p[4]  : dotv;
    dotv = (cs == 5)  ? p[5]  : dotv;
    dotv = (cs == 6)  ? p[6]  : dotv;
    dotv = (cs == 7)  ? p[7]  : dotv;
    dotv = (cs == 8)  ? p[8]  : dotv;
    dotv = (cs == 9)  ? p[9]  : dotv;
    dotv = (cs == 10) ? p[10] : dotv;
    dotv = (cs == 11) ? p[11] : dotv;
    dotv = (cs == 12) ? p[12] : dotv;
    dotv = (cs == 13) ? p[13] : dotv;
    dotv = (cs == 14) ? p[14] : dotv;
    dotv = (cs == 15) ? p[15] : dotv;
    dotv += __shfl_xor(dotv, 16);
    dotv += __shfl_xor(dotv, 32);

    unsigned long long k16 = 0xFFFFFFFFFFFFFFFFull;
    const int jl = (int)(v & 0x1FFFu);
    if (lane < NCAND) {
        const float d2x = (sqX[i] + sqX[jl]) - 2.0f * dotv;
        k16 = ((unsigned long long)__float_as_uint(d2x) << 32) | (unsigned)jl;
    }
    #pragma unroll
    for (int kk = 2; kk <= 16; kk <<= 1) {
        #pragma unroll
        for (int jj = kk >> 1; jj > 0; jj >>= 1) {
            const unsigned long long o = __shfl_xor(k16, jj);
            const bool keepmin = ((lane & kk) == 0) == ((lane & jj) == 0);
            k16 = keepmin ? (k16 < o ? k16 : o) : (k16 < o ? o : k16);
        }
    }

    // lanes 0..4 hold the exact top-5 ascending
    const float d2k = __uint_as_float((uint32_t)(k16 >> 32));
    const int   jk  = (int)(k16 & 0x1FFFull);
    float lkx = 0.0f;
    if (lane < KNN) lkx = log10f(sqrtf(fmaxf(d2k, 0.0f)) + EPS);
    const float l4x = __shfl(lkx, KNN - 1);
    float sx = lkx;
    sx += __shfl_xor(sx, 1);
    sx += __shfl_xor(sx, 2);
    sx += __shfl_xor(sx, 4);

    // z-distances, coalesced: 1 dim/lane; 5 neighbor rows read by the whole wave
    const float zi = Z[(size_t)i * DZ + lane];
    float zsum = 0.0f, l4z = 0.0f;
    #pragma unroll
    for (int k = 0; k < KNN; ++k) {
        const int jz = __shfl(jk, k);
        const float zj = Z[(size_t)jz * DZ + lane];
        const float d = zi - zj;
        float s = d * d;
        s += __shfl_xor(s, 1);
        s += __shfl_xor(s, 2);
        s += __shfl_xor(s, 4);
        s += __shfl_xor(s, 8);
        s += __shfl_xor(s, 16);
        s += __shfl_xor(s, 32);
        const float lk = log10f(sqrtf(fmaxf(s, 0.0f)) + EPS);
        zsum += lk;
        if (k == KNN - 1) l4z = lk;     // compile-time branch (unrolled)
    }

    if (lane == 0) {
        const float lx = -(__shfl(sx, 0) - (float)KNN * l4x);
        const float lz = -(zsum - (float)KNN * l4z);
        const float diff = lx - lz;
        wsum[wv] = diff * diff * (1.0f / ((float)NR * KNN * 10.0f));
    }
    __syncthreads();
    if (threadIdx.x == 0)
        atomicAdd(out, wsum[0] + wsum[1] + wsum[2] + wsum[3]);
}

// ---------------------------------------------------------------- launch
extern "C" void kernel_launch(void* const* d_in, const int* in_sizes, int n_in,
                              void* d_out, int out_size, void* d_ws, size_t ws_size,
                              hipStream_t stream) {
    const float* X = (const float*)d_in[0];
    const float* Z = (const float*)d_in[1];
    float* out = (float*)d_out;

    char* ws = (char*)d_ws;
    float*     sqX      = (float*)ws;                         // 32 KB
    uint32_t*  partials = (uint32_t*)(ws + 32768);            // 8192*48*4 = 1.57 MB
    uint8_t*   Xq       = (uint8_t*)(ws + 32768 + 2097152);   // 2 MB fp8

    split_k<<<NR / 4, 256, 0, stream>>>(X, Xq, sqX, out);
    mfma_topk_k<<<(NR / RBLK) * NSPLIT, 256, 0, stream>>>(Xq, sqX, partials);
    finalize_k<<<NR / 4, 256, 0, stream>>>(partials, X, Z, sqX, out);
}

// Round 9
// 136.617 us; speedup vs baseline: 1.2524x; 1.2524x over previous
//
#include <hip/hip_runtime.h>
#include <math.h>
#include <stdint.h>

#define EPS     1e-7f
#define NR      8192
#define DX      256             // also bytes per fp8 row
#define DZ      64
#define KNN     5
#define KEEP    6               // per-split kept candidates (packed u32)
#define NSPLIT  8
#define NPOOL   (NSPLIT * KEEP) // 48
#define NCAND   8               // exact-recompute pool in finalize (was 16; >=14 sigma safe)
#define JS      (NR / NSPLIT)   // 1024
#define JT      64              // j-cols staged per chunk
#define NCHUNK  (JS / JT)       // 16
#define RBLK    64              // i-rows per block
#define SC1     0x7F7F7F7F     // E8M0 scales = 1.0 in every byte (opsel-proof)
#define BIASF   256.0f          // C-seed bias: acc = dot - sqj/2 - 256 < 0 always (24 sigma)

typedef float f32x4 __attribute__((ext_vector_type(4)));
typedef int   i32x8 __attribute__((ext_vector_type(8)));

// guaranteed v_min_u32/v_max_u32 (ternary select can compile to v_cmp+v_cndmask = 2 ops)
__device__ __forceinline__ uint32_t umin_(uint32_t a, uint32_t b) {
    return __builtin_elementwise_min(a, b);
}
__device__ __forceinline__ uint32_t umax_(uint32_t a, uint32_t b) {
    return __builtin_elementwise_max(a, b);
}

// float -> OCP e4m3fn, round-nearest (ties-away; bias irrelevant at this noise level)
__device__ __forceinline__ uint32_t to_e4m3(float f) {
    const uint32_t u = __float_as_uint(f);
    const uint32_t s = (u >> 24) & 0x80u;
    const int e = (int)((u >> 23) & 0xFFu) - 127;
    if (e < -10) return s;                         // underflow to +/-0
    if (e > 8)   return s | 0x7Eu;                 // clamp to 448 (never for N(0,1))
    const uint32_t mant = (u & 0x7FFFFFu) | 0x800000u;
    const int shift = (e < -6) ? (14 - e) : 20;    // subnormal: extra shift
    uint32_t q = (mant + (1u << (shift - 1))) >> shift;
    int E = (e < -6) ? 0 : (e + 7);
    if (q >= 16) { q >>= 1; E += 1; }              // normal rounding carry
    if (E == 0) return s | q;                      // q==8 encodes E=1,m=0 naturally
    return s | ((uint32_t)E << 3) | (q & 7u);
}

// ------------------------------------------------- X -> fp8 + row sq-sums (+ zero out)
__global__ __launch_bounds__(256) void split_k(const float* __restrict__ X,
                                               uint8_t* __restrict__ Xq,
                                               float* __restrict__ sqX,
                                               float* __restrict__ out) {
    if (blockIdx.x == 0 && threadIdx.x == 0) out[0] = 0.0f;  // finalize runs later on stream
    const int row  = blockIdx.x * 4 + (threadIdx.x >> 6);
    const int lane = threadIdx.x & 63;
    const float4 v = *(const float4*)&X[(size_t)row * DX + lane * 4];
    float s = v.x * v.x + v.y * v.y + v.z * v.z + v.w * v.w;
    const uint32_t b = to_e4m3(v.x) | (to_e4m3(v.y) << 8) |
                       (to_e4m3(v.z) << 16) | (to_e4m3(v.w) << 24);
    ((uint32_t*)Xq)[(size_t)row * (DX / 4) + lane] = b;
    #pragma unroll
    for (int o = 32; o > 0; o >>= 1) s += __shfl_down(s, o);
    if (lane == 0) sqX[row] = s;
}

// ------------------------------------------------- MX-fp8 K=128 MFMA GEMM + packed top-4
// R8 POST-MORTEM: barrier-free L2-streaming collapsed BOTH pipes (VALU 28%, Mfma 8%,
// 79.6us) -- unpipelined L2 latency on 128 serial VMEM round-trips/wave. The LDS-staged
// dbuf structure (R5, 45.4us) is the proven local optimum; reverted to it verbatim.
// Structure: double-buffered global_load_lds staging, ONE barrier per chunk; per-lane
// sorted-4 fold ((2,4) rank-merge, min3-shaped, branchless); stage-1 epilogue merges
// (4,4)->sorted-5 across lane pairs, butterfly (5,5)->5, cross-wave KEEP=6.
// Sorted-4 safe: dropping a true top-5 neighbor needs 5-of-5 in one 32-cand lane-stream:
// P=(1/256)^4/row -> 2e-6 over 8192 rows.
// Key is a per-row monotone transform of d2 (C-seeded with -sqj/2-256; all-negative ->
// uint-monotone) -> selection unchanged; finalize re-ranks exactly in fp32.
// CORRECTNESS/PERF NOTES (hard-won):
//  * NO runtime subscripts into register arrays (R5: 711 MB scratch). Constant-index only.
//  * NO branches in the fold (R2: exec-guard serialized the ILP networks, always taken).
//  * NO reg-streaming of B from L2 (R8: compiler won't pipeline past acc dep chain).
#define FOLD_BODY(KILL)                                                                   \
    _Pragma("unroll")                                                                     \
    for (int g = 0; g < 2; ++g) {                                                         \
        _Pragma("unroll")                                                                 \
        for (int r = 0; r < 4; ++r) {                                                     \
            const int q = g * 4 + r;                                                      \
            uint32_t c0 = (__float_as_uint(acc[0][g][r]) & 0xFFFFE000u) | (uint32_t)j0;   \
            uint32_t c1 = (__float_as_uint(acc[1][g][r]) & 0xFFFFE000u) | (uint32_t)j1;   \
            if (KILL) {                                                                   \
                const int irow = rowbase + g * 16 + quad * 4 + r;                         \
                c0 = (j0 == irow) ? 0xFFFFFFFFu : c0;                                     \
                c1 = (j1 == irow) ? 0xFFFFFFFFu : c1;                                     \
            }                                                                             \
            const uint32_t lo = umin_(c0, c1);                                            \
            const uint32_t hi = umax_(c0, c1);                                            \
            const uint32_t b0 = best[q][0], b1 = best[q][1], b2 = best[q][2],             \
                           b3 = best[q][3];                                               \
            best[q][0] = umin_(b0, lo);                                                   \
            best[q][1] = umin_(umin_(b1, hi), umax_(b0, lo));                             \
            best[q][2] = umin_(umin_(b2, umax_(b1, lo)), umax_(b0, hi));                  \
            best[q][3] = umin_(umin_(b3, umax_(b2, lo)), umax_(b1, hi));                  \
        }                                                                                 \
    }

// stage chunk t of this block's split into buf[t&1]; advances srcp
#define STAGE(t) do {                                                                     \
    uint8_t* const _base = &smem[(t) & 1][0];                                             \
    _Pragma("unroll")                                                                     \
    for (int u = 0; u < 4; ++u) {                                                         \
        __builtin_amdgcn_global_load_lds(                                                 \
            (const __attribute__((address_space(1))) uint32_t*)srcp[u],                   \
            (__attribute__((address_space(3))) uint32_t*)(_base + dstoff[u]),             \
            16, 0, 0);                                                                    \
        srcp[u] += JT * DX;                                                               \
    }                                                                                     \
} while (0)

__global__ __launch_bounds__(256, 2) void mfma_topk_k(const uint8_t* __restrict__ Xq,
                                                      const float* __restrict__ sqX,
                                                      uint32_t* __restrict__ partials) {
    __shared__ __align__(16) uint8_t smem[2][16384];   // B staging dbuf: 2 x 1024 x 16 B
    __shared__ uint32_t mb2[RBLK][2][KNN];             // cross-wave merge (2.5 KB)
    __shared__ __align__(16) float sq_s[JS];           // split's sqX slice (4 KB)

    const int tid  = threadIdx.x;
    const int w    = tid >> 6;
    const int lane = tid & 63;
    const int n    = lane & 15;
    const int quad = lane >> 4;
    const int x7   = n & 7;
    const int h    = w >> 1;
    const int sp   = w & 1;
    const int s    = blockIdx.x & 7;                   // split (XCD round-robin)
    const int ib   = (blockIdx.x >> 3) * RBLK;
    const int jb0  = s * JS;
    const int rowbase = ib + h * 32;

    // stage the split's sqX slice (read per chunk, quad-broadcast -> conflict-free)
    ((f32x4*)sq_s)[tid] = ((const f32x4*)(sqX + jb0))[tid];

    // diagonal lives in exactly one chunk per wave (or none); scalar-branch key
    const int rel   = rowbase - jb0;
    const int cdiag = __builtin_amdgcn_readfirstlane((rel >= 0 && rel < JS) ? (rel >> 6) : -1);

    // A fragments: 2 rowgroups x 2 K-halves of 128 (32 B = i32x8 each; 32 VGPR total)
    i32x8 Aq[2][2];
    #pragma unroll
    for (int g = 0; g < 2; ++g)
        #pragma unroll
        for (int kf = 0; kf < 2; ++kf)
            Aq[g][kf] = *(const i32x8*)(Xq + (size_t)(rowbase + g * 16 + n) * DX
                                        + kf * 128 + quad * 32);

    uint32_t best[8][4];     // q = g*4+r; ascending sorted-4; compile-time indices only
    #pragma unroll
    for (int q = 0; q < 8; ++q)
        #pragma unroll
        for (int k = 0; k < 4; ++k) best[q][k] = 0xFFFFFFFFu;

    // hoisted chunk-invariant addressing ------------------------------------------------
    // staging map: slot q = w*256 + u*64 + lane holds col sj=q>>4, chunk c=(q&15)^(sj&7)
    const uint8_t* srcp[4];
    int            dstoff[4];
    #pragma unroll
    for (int u = 0; u < 4; ++u) {
        const int q  = w * 256 + u * 64 + lane;
        const int sj = q >> 4;
        const int c  = (q & 15) ^ (sj & 7);
        srcp[u]   = Xq + (size_t)jb0 * DX + sj * DX + c * 16;
        dstoff[u] = (w * 256 + u * 64) * 16;           // uniform; HW adds +lane*16
    }
    // 8 LDS B-slot indices (uint4 units): [kf][si][pair]
    int bidx[2][2][2];
    #pragma unroll
    for (int kf = 0; kf < 2; ++kf)
        #pragma unroll
        for (int si = 0; si < 2; ++si) {
            const int sj = (sp * 2 + si) * 16 + n;
            const int cb = kf * 8 + quad * 2;
            bidx[kf][si][0] = sj * 16 + (cb ^ x7);
            bidx[kf][si][1] = sj * 16 + ((cb + 1) ^ x7);
        }
    const float* sqp = sq_s + sp * 32 + n;             // +64 floats per chunk
    int j0 = jb0 + sp * 32 + n;                        // +JT per chunk; j1 = j0+16

    STAGE(0);                                          // prologue: chunk 0 -> buf0

    for (int jc = 0; jc < NCHUNK; ++jc) {
        // compiler emits s_waitcnt vmcnt(0) + s_barrier: the drain waits on loads issued
        // one full compute phase ago (covered) -> buf[jc&1] visible to all waves
        __syncthreads();
        if (jc + 1 < NCHUNK) STAGE(jc + 1);            // prefetch into buf^1, latency
                                                       // hidden under this chunk's compute
        const uint4* Bv = (const uint4*)&smem[jc & 1][0];

        // C-seed: acc starts at -sqj/2 - 256 so final acc bits are the ranking key
        const float ini0 = fmaf(-0.5f, sqp[jc * JT],      -BIASF);
        const float ini1 = fmaf(-0.5f, sqp[jc * JT + 16], -BIASF);

        f32x4 acc[2][2];  // [si][g]
        #pragma unroll
        for (int g = 0; g < 2; ++g)
            #pragma unroll
            for (int r = 0; r < 4; ++r) { acc[0][g][r] = ini0; acc[1][g][r] = ini1; }

        #pragma unroll
        for (int kf = 0; kf < 2; ++kf) {
            #pragma unroll
            for (int si = 0; si < 2; ++si) {
                union { uint4 p[2]; i32x8 v; } bb;
                bb.p[0] = Bv[bidx[kf][si][0]];
                bb.p[1] = Bv[bidx[kf][si][1]];
                acc[si][0] = __builtin_amdgcn_mfma_scale_f32_16x16x128_f8f6f4(
                                 Aq[0][kf], bb.v, acc[si][0], 0, 0, 0, SC1, 0, SC1);
                acc[si][1] = __builtin_amdgcn_mfma_scale_f32_16x16x128_f8f6f4(
                                 Aq[1][kf], bb.v, acc[si][1], 0, 0, 0, SC1, 0, SC1);
            }
        }

        // fold 16 candidates/lane as 8 sorted-pairs merged into sorted-4
        // (C layout: col=n, row=quad*4+reg; key = acc bits, all-negative -> uint-monotone)
        const int j1 = j0 + 16;
        if (jc != cdiag) {
            FOLD_BODY(0)
        } else {
            FOLD_BODY(1)
        }
        j0 += JT;
    }

    // per-q: stage 1 merges sorted-4 pairs -> sorted-5, stages 2-4 butterfly (5,5)->5,
    // then LDS dump. From stage 2 on capacity is 5 -> split-level guarantees unchanged.
    #pragma unroll
    for (int q = 0; q < 8; ++q) {
        const uint32_t s0 = best[q][0], s1 = best[q][1], s2 = best[q][2], s3 = best[q][3];
        const uint32_t t0 = __shfl_xor(s0, 1);
        const uint32_t t1 = __shfl_xor(s1, 1);
        const uint32_t t2 = __shfl_xor(s2, 1);
        const uint32_t t3 = __shfl_xor(s3, 1);
        // (4,4) -> sorted-5
        uint32_t a0 = umin_(s0, t0);
        uint32_t a1 = umin_(umin_(s1, t1), umax_(s0, t0));
        uint32_t a2 = umin_(umin_(s2, t2), umin_(umax_(s1, t0), umax_(s0, t1)));
        uint32_t a3 = umin_(umin_(s3, t3),
                            umin_(umax_(s2, t0), umin_(umax_(s1, t1), umax_(s0, t2))));
        uint32_t a4 = umin_(umin_(umax_(s3, t0), umax_(s2, t1)),
                            umin_(umax_(s1, t2), umax_(s0, t3)));
        #pragma unroll
        for (int mask = 2; mask <= 8; mask <<= 1) {
            const uint32_t b0 = __shfl_xor(a0, mask);
            const uint32_t b1 = __shfl_xor(a1, mask);
            const uint32_t b2 = __shfl_xor(a2, mask);
            const uint32_t b3 = __shfl_xor(a3, mask);
            const uint32_t b4 = __shfl_xor(a4, mask);
            const uint32_t c0 = umin_(a0, b0);
            const uint32_t c1 = umin_(umin_(a1, b1), umax_(a0, b0));
            const uint32_t c2 = umin_(umin_(a2, b2), umin_(umax_(a0, b1), umax_(a1, b0)));
            const uint32_t c3 = umin_(umin_(a3, b3),
                                      umin_(umax_(a1, b1), umin_(umax_(a0, b2), umax_(a2, b0))));
            const uint32_t c4 = umin_(umin_(a4, b4),
                                      umin_(umin_(umax_(a0, b3), umax_(a1, b2)),
                                            umin_(umax_(a2, b1), umax_(a3, b0))));
            a0 = c0; a1 = c1; a2 = c2; a3 = c3; a4 = c4;
        }
        const int rloc = h * 32 + (q >> 2) * 16 + quad * 4 + (q & 3);
        uint32_t v = a0;                 // lane n emits element n via constant select chain
        v = (n == 1) ? a1 : v;
        v = (n == 2) ? a2 : v;
        v = (n == 3) ? a3 : v;
        v = (n == 4) ? a4 : v;
        if (n < KNN) mb2[rloc][sp][n] = v;
    }
    __syncthreads();

    // cross-wave (sp) merge; emit KEEP=6 per row per split
    if (tid < RBLK) {
        const uint32_t a0 = mb2[tid][0][0], a1 = mb2[tid][0][1], a2 = mb2[tid][0][2],
                       a3 = mb2[tid][0][3], a4 = mb2[tid][0][4];
        const uint32_t b0 = mb2[tid][1][0], b1 = mb2[tid][1][1], b2 = mb2[tid][1][2],
                       b3 = mb2[tid][1][3], b4 = mb2[tid][1][4];
        uint32_t o[KEEP];
        o[0] = umin_(a0, b0);
        o[1] = umin_(umin_(a1, b1), umax_(a0, b0));
        o[2] = umin_(umin_(a2, b2), umin_(umax_(a0, b1), umax_(a1, b0)));
        o[3] = umin_(umin_(a3, b3), umin_(umax_(a1, b1), umin_(umax_(a0, b2), umax_(a2, b0))));
        o[4] = umin_(umin_(a4, b4), umin_(umin_(umax_(a0, b3), umax_(a1, b2)),
                                          umin_(umax_(a2, b1), umax_(a3, b0))));
        o[5] = umin_(umin_(umax_(a0, b4), umax_(a4, b0)),
                     umin_(umax_(a1, b3), umin_(umax_(a2, b2), umax_(a3, b1))));
        #pragma unroll
        for (int k = 0; k < KEEP; ++k)
            partials[(size_t)(ib + tid) * NPOOL + s * KEEP + k] = o[k];
    }
}

// ------------------------------------------------- one wave per row, ROW-COALESCED re-rank:
// bitonic-64 approx sort of the 48-pool; per candidate, all 64 lanes read its X row
// (coalesced); butterfly-reduced exact fp32 dots; bitonic-8 exact (d2,j) sort; lid; loss.
// NCAND 16->8 (R9): order-stat spacing at ranks 5-8 is ~6.5 d2-units/rank vs fp8-key
// noise sigma ~2 -> true-top-5 escaping approx-top-8 is a >=14 sigma event per row.
// Halves candidate row loads + dot shuffles; bitonic-16 -> bitonic-8 on 64-bit keys.
__global__ __launch_bounds__(256) void finalize_k(const uint32_t* __restrict__ parts,
                                                  const float* __restrict__ X,
                                                  const float* __restrict__ Z,
                                                  const float* __restrict__ sqX,
                                                  float* __restrict__ out) {
    __shared__ float wsum[4];
    const int wv   = threadIdx.x >> 6;
    const int lane = threadIdx.x & 63;
    const int i    = blockIdx.x * 4 + wv;

    // bitonic sort the pool across lanes (keys distinct: disjoint j; inert lanes = FFFF)
    uint32_t v = (lane < NPOOL) ? parts[(size_t)i * NPOOL + lane] : 0xFFFFFFFFu;
    #pragma unroll
    for (int kk = 2; kk <= 64; kk <<= 1) {
        #pragma unroll
        for (int jj = kk >> 1; jj > 0; jj >>= 1) {
            const uint32_t o = __shfl_xor(v, jj);
            const bool keepmin = ((lane & kk) == 0) == ((lane & jj) == 0);
            v = keepmin ? umin_(v, o) : umax_(v, o);
        }
    }
    // lanes 0..7 hold the approx top-8 ascending

    const float4 xi = *(const float4*)(X + (size_t)i * DX + lane * 4);

    float p[NCAND];
    #pragma unroll
    for (int c = 0; c < NCAND; ++c) {
        const int jc = (int)(__shfl(v, c) & 0x1FFFu);
        const float4 xj = *(const float4*)(X + (size_t)jc * DX + lane * 4);
        p[c] = fmaf(xi.x, xj.x, fmaf(xi.y, xj.y, fmaf(xi.z, xj.z, xi.w * xj.w)));
    }
    #pragma unroll
    for (int c = 0; c < NCAND; ++c) {
        p[c] += __shfl_xor(p[c], 1);
        p[c] += __shfl_xor(p[c], 2);
        p[c] += __shfl_xor(p[c], 4);
        p[c] += __shfl_xor(p[c], 8);
    }
    // p[c] = partial over this 16-lane group's 64 dims; select candidate cs, then sum
    // the 4 group partials via xor 16/32. Only cs<8 used downstream.
    const int cs = lane & 15;
    float dotv = p[0];
    dotv = (cs == 1) ? p[1] : dotv;
    dotv = (cs == 2) ? p[2] : dotv;
    dotv = (cs == 3) ? p[3] : dotv;
    dotv = (cs == 4) ? p[4] : dotv;
    dotv = (cs == 5) ? p[5] : dotv;
    dotv = (cs == 6) ? p[6] : dotv;
    dotv = (cs == 7) ? p[7] : dotv;
    dotv += __shfl_xor(dotv, 16);
    dotv += __shfl_xor(dotv, 32);

    unsigned long long k16 = 0xFFFFFFFFFFFFFFFFull;
    const int jl = (int)(v & 0x1FFFu);
    if (lane < NCAND) {
        const float d2x = (sqX[i] + sqX[jl]) - 2.0f * dotv;
        k16 = ((unsigned long long)__float_as_uint(d2x) << 32) | (unsigned)jl;
    }
    #pragma unroll
    for (int kk = 2; kk <= NCAND; kk <<= 1) {
        #pragma unroll
        for (int jj = kk >> 1; jj > 0; jj >>= 1) {
            const unsigned long long o = __shfl_xor(k16, jj);
            const bool keepmin = ((lane & kk) == 0) == ((lane & jj) == 0);
            k16 = keepmin ? (k16 < o ? k16 : o) : (k16 < o ? o : k16);
        }
    }

    // lanes 0..4 hold the exact top-5 ascending
    const float d2k = __uint_as_float((uint32_t)(k16 >> 32));
    const int   jk  = (int)(k16 & 0x1FFFull);
    float lkx = 0.0f;
    if (lane < KNN) lkx = log10f(sqrtf(fmaxf(d2k, 0.0f)) + EPS);
    const float l4x = __shfl(lkx, KNN - 1);
    float sx = lkx;
    sx += __shfl_xor(sx, 1);
    sx += __shfl_xor(sx, 2);
    sx += __shfl_xor(sx, 4);

    // z-distances, coalesced: 1 dim/lane; 5 neighbor rows read by the whole wave
    const float zi = Z[(size_t)i * DZ + lane];
    float zsum = 0.0f, l4z = 0.0f;
    #pragma unroll
    for (int k = 0; k < KNN; ++k) {
        const int jz = __shfl(jk, k);
        const float zj = Z[(size_t)jz * DZ + lane];
        const float d = zi - zj;
        float s = d * d;
        s += __shfl_xor(s, 1);
        s += __shfl_xor(s, 2);
        s += __shfl_xor(s, 4);
        s += __shfl_xor(s, 8);
        s += __shfl_xor(s, 16);
        s += __shfl_xor(s, 32);
        const float lk = log10f(sqrtf(fmaxf(s, 0.0f)) + EPS);
        zsum += lk;
        if (k == KNN - 1) l4z = lk;     // compile-time branch (unrolled)
    }

    if (lane == 0) {
        const float lx = -(__shfl(sx, 0) - (float)KNN * l4x);
        const float lz = -(zsum - (float)KNN * l4z);
        const float diff = lx - lz;
        wsum[wv] = diff * diff * (1.0f / ((float)NR * KNN * 10.0f));
    }
    __syncthreads();
    if (threadIdx.x == 0)
        atomicAdd(out, wsum[0] + wsum[1] + wsum[2] + wsum[3]);
}

// ---------------------------------------------------------------- launch
extern "C" void kernel_launch(void* const* d_in, const int* in_sizes, int n_in,
                              void* d_out, int out_size, void* d_ws, size_t ws_size,
                              hipStream_t stream) {
    const float* X = (const float*)d_in[0];
    const float* Z = (const float*)d_in[1];
    float* out = (float*)d_out;

    char* ws = (char*)d_ws;
    float*     sqX      = (float*)ws;                         // 32 KB
    uint32_t*  partials = (uint32_t*)(ws + 32768);            // 8192*48*4 = 1.57 MB
    uint8_t*   Xq       = (uint8_t*)(ws + 32768 + 2097152);   // 2 MB fp8

    split_k<<<NR / 4, 256, 0, stream>>>(X, Xq, sqX, out);
    mfma_topk_k<<<(NR / RBLK) * NSPLIT, 256, 0, stream>>>(Xq, sqX, partials);
    finalize_k<<<NR / 4, 256, 0, stream>>>(partials, X, Z, sqX, out);
}

// Round 10
// 136.315 us; speedup vs baseline: 1.2552x; 1.0022x over previous
//
#include <hip/hip_runtime.h>
#include <math.h>
#include <stdint.h>

#define EPS     1e-7f
#define NR      8192
#define DX      256             // also bytes per fp8 row
#define DZ      64
#define KNN     5
#define KEEP    6               // per-split kept candidates (packed u32)
#define NSPLIT  8
#define NPOOL   (NSPLIT * KEEP) // 48
#define NCAND   16              // exact-recompute pool in finalize (self + 15 neighbors)
#define JS      (NR / NSPLIT)   // 1024
#define JT      64              // j-cols staged per chunk
#define NCHUNK  (JS / JT)       // 16
#define RBLK    64              // i-rows per block
#define SC1     0x7F7F7F7F     // E8M0 scales = 1.0 in every byte (opsel-proof)
#define BIASF   256.0f          // C-seed bias: acc = dot - sqj/2 - 256 < 0 always (24 sigma)

typedef float f32x4 __attribute__((ext_vector_type(4)));
typedef int   i32x8 __attribute__((ext_vector_type(8)));

// guaranteed v_min_u32/v_max_u32 (ternary select can compile to v_cmp+v_cndmask = 2 ops)
__device__ __forceinline__ uint32_t umin_(uint32_t a, uint32_t b) {
    return __builtin_elementwise_min(a, b);
}
__device__ __forceinline__ uint32_t umax_(uint32_t a, uint32_t b) {
    return __builtin_elementwise_max(a, b);
}

// float -> OCP e4m3fn, round-nearest (ties-away; bias irrelevant at this noise level)
__device__ __forceinline__ uint32_t to_e4m3(float f) {
    const uint32_t u = __float_as_uint(f);
    const uint32_t s = (u >> 24) & 0x80u;
    const int e = (int)((u >> 23) & 0xFFu) - 127;
    if (e < -10) return s;                         // underflow to +/-0
    if (e > 8)   return s | 0x7Eu;                 // clamp to 448 (never for N(0,1))
    const uint32_t mant = (u & 0x7FFFFFu) | 0x800000u;
    const int shift = (e < -6) ? (14 - e) : 20;    // subnormal: extra shift
    uint32_t q = (mant + (1u << (shift - 1))) >> shift;
    int E = (e < -6) ? 0 : (e + 7);
    if (q >= 16) { q >>= 1; E += 1; }              // normal rounding carry
    if (E == 0) return s | q;                      // q==8 encodes E=1,m=0 naturally
    return s | ((uint32_t)E << 3) | (q & 7u);
}

// ------------------------------------------------- X -> fp8 + row sq-sums (+ zero out)
__global__ __launch_bounds__(256) void split_k(const float* __restrict__ X,
                                               uint8_t* __restrict__ Xq,
                                               float* __restrict__ sqX,
                                               float* __restrict__ out) {
    if (blockIdx.x == 0 && threadIdx.x == 0) out[0] = 0.0f;  // finalize runs later on stream
    const int row  = blockIdx.x * 4 + (threadIdx.x >> 6);
    const int lane = threadIdx.x & 63;
    const float4 v = *(const float4*)&X[(size_t)row * DX + lane * 4];
    float s = v.x * v.x + v.y * v.y + v.z * v.z + v.w * v.w;
    const uint32_t b = to_e4m3(v.x) | (to_e4m3(v.y) << 8) |
                       (to_e4m3(v.z) << 16) | (to_e4m3(v.w) << 24);
    ((uint32_t*)Xq)[(size_t)row * (DX / 4) + lane] = b;
    #pragma unroll
    for (int o = 32; o > 0; o >>= 1) s += __shfl_down(s, o);
    if (lane == 0) sqX[row] = s;
}

// ------------------------------------------------- MX-fp8 K=128 MFMA GEMM + packed top-4
// R10: diagonal kill DELETED from the hot loop. Self (j==i) flows through: its acc is the
// row's guaranteed-minimal key (d2=0 under the monotone map; acc_self ~ -128 vs -384+-16
// for others, uint-monotone) -> rank 0 of its stream/split/pool, occupying exactly one
// slot (KEEP=6 = self + 5 -> split guarantees intact; 4-of-top-5 colliding into the self
// stream is (1/256)^4/row ~ 2e-10). finalize drops self exactly (key forced to 0, take
// lanes 1..5). This collapses the loop to ONE branch-free FOLD_BODY, no cdiag.
// Structure (proven R5 optimum): double-buffered global_load_lds staging, ONE barrier per
// chunk; per-lane sorted-4 fold ((2,4) rank-merge, min3-shaped, branchless); epilogue
// (4,4)->sorted-5, butterfly (5,5)->5, cross-wave KEEP=6.
// Sorted-4 safe: dropping a true top-5 neighbor needs 5-of-5 in one 32-cand lane-stream:
// P=(1/256)^4/row -> 2e-6 over 8192 rows.
// CORRECTNESS/PERF NOTES (hard-won):
//  * NO runtime subscripts into register arrays (R5: 711 MB scratch). Constant-index only.
//  * NO branches in the fold (R2: exec-guard serialized the ILP networks, always taken).
//  * NO reg-streaming of B from L2 (R8: compiler won't pipeline past acc dep chain;
//    barrier-free L2 streaming collapsed both pipes, 79.6us).
#define FOLD_BODY()                                                                       \
    _Pragma("unroll")                                                                     \
    for (int g = 0; g < 2; ++g) {                                                         \
        _Pragma("unroll")                                                                 \
        for (int r = 0; r < 4; ++r) {                                                     \
            const int q = g * 4 + r;                                                      \
            const uint32_t c0 = (__float_as_uint(acc[0][g][r]) & 0xFFFFE000u) | (uint32_t)j0; \
            const uint32_t c1 = (__float_as_uint(acc[1][g][r]) & 0xFFFFE000u) | (uint32_t)j1; \
            const uint32_t lo = umin_(c0, c1);                                            \
            const uint32_t hi = umax_(c0, c1);                                            \
            const uint32_t b0 = best[q][0], b1 = best[q][1], b2 = best[q][2],             \
                           b3 = best[q][3];                                               \
            best[q][0] = umin_(b0, lo);                                                   \
            best[q][1] = umin_(umin_(b1, hi), umax_(b0, lo));                             \
            best[q][2] = umin_(umin_(b2, umax_(b1, lo)), umax_(b0, hi));                  \
            best[q][3] = umin_(umin_(b3, umax_(b2, lo)), umax_(b1, hi));                  \
        }                                                                                 \
    }

// stage chunk t of this block's split into buf[t&1]; advances srcp
#define STAGE(t) do {                                                                     \
    uint8_t* const _base = &smem[(t) & 1][0];                                             \
    _Pragma("unroll")                                                                     \
    for (int u = 0; u < 4; ++u) {                                                         \
        __builtin_amdgcn_global_load_lds(                                                 \
            (const __attribute__((address_space(1))) uint32_t*)srcp[u],                   \
            (__attribute__((address_space(3))) uint32_t*)(_base + dstoff[u]),             \
            16, 0, 0);                                                                    \
        srcp[u] += JT * DX;                                                               \
    }                                                                                     \
} while (0)

__global__ __launch_bounds__(256, 2) void mfma_topk_k(const uint8_t* __restrict__ Xq,
                                                      const float* __restrict__ sqX,
                                                      uint32_t* __restrict__ partials) {
    __shared__ __align__(16) uint8_t smem[2][16384];   // B staging dbuf: 2 x 1024 x 16 B
    __shared__ uint32_t mb2[RBLK][2][KNN];             // cross-wave merge (2.5 KB)
    __shared__ __align__(16) float sq_s[JS];           // split's sqX slice (4 KB)

    const int tid  = threadIdx.x;
    const int w    = tid >> 6;
    const int lane = tid & 63;
    const int n    = lane & 15;
    const int quad = lane >> 4;
    const int x7   = n & 7;
    const int h    = w >> 1;
    const int sp   = w & 1;
    const int s    = blockIdx.x & 7;                   // split (XCD round-robin)
    const int ib   = (blockIdx.x >> 3) * RBLK;
    const int jb0  = s * JS;
    const int rowbase = ib + h * 32;

    // stage the split's sqX slice (read per chunk, quad-broadcast -> conflict-free)
    ((f32x4*)sq_s)[tid] = ((const f32x4*)(sqX + jb0))[tid];

    // A fragments: 2 rowgroups x 2 K-halves of 128 (32 B = i32x8 each; 32 VGPR total)
    i32x8 Aq[2][2];
    #pragma unroll
    for (int g = 0; g < 2; ++g)
        #pragma unroll
        for (int kf = 0; kf < 2; ++kf)
            Aq[g][kf] = *(const i32x8*)(Xq + (size_t)(rowbase + g * 16 + n) * DX
                                        + kf * 128 + quad * 32);

    uint32_t best[8][4];     // q = g*4+r; ascending sorted-4; compile-time indices only
    #pragma unroll
    for (int q = 0; q < 8; ++q)
        #pragma unroll
        for (int k = 0; k < 4; ++k) best[q][k] = 0xFFFFFFFFu;

    // hoisted chunk-invariant addressing ------------------------------------------------
    // staging map: slot q = w*256 + u*64 + lane holds col sj=q>>4, chunk c=(q&15)^(sj&7)
    const uint8_t* srcp[4];
    int            dstoff[4];
    #pragma unroll
    for (int u = 0; u < 4; ++u) {
        const int q  = w * 256 + u * 64 + lane;
        const int sj = q >> 4;
        const int c  = (q & 15) ^ (sj & 7);
        srcp[u]   = Xq + (size_t)jb0 * DX + sj * DX + c * 16;
        dstoff[u] = (w * 256 + u * 64) * 16;           // uniform; HW adds +lane*16
    }
    // 8 LDS B-slot indices (uint4 units): [kf][si][pair]
    int bidx[2][2][2];
    #pragma unroll
    for (int kf = 0; kf < 2; ++kf)
        #pragma unroll
        for (int si = 0; si < 2; ++si) {
            const int sj = (sp * 2 + si) * 16 + n;
            const int cb = kf * 8 + quad * 2;
            bidx[kf][si][0] = sj * 16 + (cb ^ x7);
            bidx[kf][si][1] = sj * 16 + ((cb + 1) ^ x7);
        }
    const float* sqp = sq_s + sp * 32 + n;             // +64 floats per chunk
    int j0 = jb0 + sp * 32 + n;                        // +JT per chunk; j1 = j0+16

    STAGE(0);                                          // prologue: chunk 0 -> buf0

    for (int jc = 0; jc < NCHUNK; ++jc) {
        // compiler emits s_waitcnt vmcnt(0) + s_barrier: the drain waits on loads issued
        // one full compute phase ago (covered) -> buf[jc&1] visible to all waves
        __syncthreads();
        if (jc + 1 < NCHUNK) STAGE(jc + 1);            // prefetch into buf^1, latency
                                                       // hidden under this chunk's compute
        const uint4* Bv = (const uint4*)&smem[jc & 1][0];

        // C-seed: acc starts at -sqj/2 - 256 so final acc bits are the ranking key
        const float ini0 = fmaf(-0.5f, sqp[jc * JT],      -BIASF);
        const float ini1 = fmaf(-0.5f, sqp[jc * JT + 16], -BIASF);

        f32x4 acc[2][2];  // [si][g]
        #pragma unroll
        for (int g = 0; g < 2; ++g)
            #pragma unroll
            for (int r = 0; r < 4; ++r) { acc[0][g][r] = ini0; acc[1][g][r] = ini1; }

        #pragma unroll
        for (int kf = 0; kf < 2; ++kf) {
            #pragma unroll
            for (int si = 0; si < 2; ++si) {
                union { uint4 p[2]; i32x8 v; } bb;
                bb.p[0] = Bv[bidx[kf][si][0]];
                bb.p[1] = Bv[bidx[kf][si][1]];
                acc[si][0] = __builtin_amdgcn_mfma_scale_f32_16x16x128_f8f6f4(
                                 Aq[0][kf], bb.v, acc[si][0], 0, 0, 0, SC1, 0, SC1);
                acc[si][1] = __builtin_amdgcn_mfma_scale_f32_16x16x128_f8f6f4(
                                 Aq[1][kf], bb.v, acc[si][1], 0, 0, 0, SC1, 0, SC1);
            }
        }

        // fold 16 candidates/lane as 8 sorted-pairs merged into sorted-4 (self included)
        // (C layout: col=n, row=quad*4+reg; key = acc bits, all-negative -> uint-monotone)
        const int j1 = j0 + 16;
        FOLD_BODY()
        j0 += JT;
    }

    // per-q: stage 1 merges sorted-4 pairs -> sorted-5, stages 2-4 butterfly (5,5)->5,
    // then LDS dump. From stage 2 on capacity is 5 -> split-level guarantees unchanged.
    #pragma unroll
    for (int q = 0; q < 8; ++q) {
        const uint32_t s0 = best[q][0], s1 = best[q][1], s2 = best[q][2], s3 = best[q][3];
        const uint32_t t0 = __shfl_xor(s0, 1);
        const uint32_t t1 = __shfl_xor(s1, 1);
        const uint32_t t2 = __shfl_xor(s2, 1);
        const uint32_t t3 = __shfl_xor(s3, 1);
        // (4,4) -> sorted-5
        uint32_t a0 = umin_(s0, t0);
        uint32_t a1 = umin_(umin_(s1, t1), umax_(s0, t0));
        uint32_t a2 = umin_(umin_(s2, t2), umin_(umax_(s1, t0), umax_(s0, t1)));
        uint32_t a3 = umin_(umin_(s3, t3),
                            umin_(umax_(s2, t0), umin_(umax_(s1, t1), umax_(s0, t2))));
        uint32_t a4 = umin_(umin_(umax_(s3, t0), umax_(s2, t1)),
                            umin_(umax_(s1, t2), umax_(s0, t3)));
        #pragma unroll
        for (int mask = 2; mask <= 8; mask <<= 1) {
            const uint32_t b0 = __shfl_xor(a0, mask);
            const uint32_t b1 = __shfl_xor(a1, mask);
            const uint32_t b2 = __shfl_xor(a2, mask);
            const uint32_t b3 = __shfl_xor(a3, mask);
            const uint32_t b4 = __shfl_xor(a4, mask);
            const uint32_t c0 = umin_(a0, b0);
            const uint32_t c1 = umin_(umin_(a1, b1), umax_(a0, b0));
            const uint32_t c2 = umin_(umin_(a2, b2), umin_(umax_(a0, b1), umax_(a1, b0)));
            const uint32_t c3 = umin_(umin_(a3, b3),
                                      umin_(umax_(a1, b1), umin_(umax_(a0, b2), umax_(a2, b0))));
            const uint32_t c4 = umin_(umin_(a4, b4),
                                      umin_(umin_(umax_(a0, b3), umax_(a1, b2)),
                                            umin_(umax_(a2, b1), umax_(a3, b0))));
            a0 = c0; a1 = c1; a2 = c2; a3 = c3; a4 = c4;
        }
        const int rloc = h * 32 + (q >> 2) * 16 + quad * 4 + (q & 3);
        uint32_t v = a0;                 // lane n emits element n via constant select chain
        v = (n == 1) ? a1 : v;
        v = (n == 2) ? a2 : v;
        v = (n == 3) ? a3 : v;
        v = (n == 4) ? a4 : v;
        if (n < KNN) mb2[rloc][sp][n] = v;
    }
    __syncthreads();

    // cross-wave (sp) merge; emit KEEP=6 per row per split (self + 5 for the home split)
    if (tid < RBLK) {
        const uint32_t a0 = mb2[tid][0][0], a1 = mb2[tid][0][1], a2 = mb2[tid][0][2],
                       a3 = mb2[tid][0][3], a4 = mb2[tid][0][4];
        const uint32_t b0 = mb2[tid][1][0], b1 = mb2[tid][1][1], b2 = mb2[tid][1][2],
                       b3 = mb2[tid][1][3], b4 = mb2[tid][1][4];
        uint32_t o[KEEP];
        o[0] = umin_(a0, b0);
        o[1] = umin_(umin_(a1, b1), umax_(a0, b0));
        o[2] = umin_(umin_(a2, b2), umin_(umax_(a0, b1), umax_(a1, b0)));
        o[3] = umin_(umin_(a3, b3), umin_(umax_(a1, b1), umin_(umax_(a0, b2), umax_(a2, b0))));
        o[4] = umin_(umin_(a4, b4), umin_(umin_(umax_(a0, b3), umax_(a1, b2)),
                                          umin_(umax_(a2, b1), umax_(a3, b0))));
        o[5] = umin_(umin_(umax_(a0, b4), umax_(a4, b0)),
                     umin_(umax_(a1, b3), umin_(umax_(a2, b2), umax_(a3, b1))));
        #pragma unroll
        for (int k = 0; k < KEEP; ++k)
            partials[(size_t)(ib + tid) * NPOOL + s * KEEP + k] = o[k];
    }
}

// ------------------------------------------------- one wave per row, ROW-COALESCED re-rank:
// bitonic-64 approx sort of the 48-pool (incl self); per candidate, all 64 lanes read its
// X row (coalesced); butterfly-reduced exact fp32 dots; bitonic-16 exact (d2,j) sort with
// self's key forced to 0 (guards d2~0 rounding negative -> would sort last); neighbors =
// lanes 1..5; lid; loss.
__global__ __launch_bounds__(256) void finalize_k(const uint32_t* __restrict__ parts,
                                                  const float* __restrict__ X,
                                                  const float* __restrict__ Z,
                                                  const float* __restrict__ sqX,
                                                  float* __restrict__ out) {
    __shared__ float wsum[4];
    const int wv   = threadIdx.x >> 6;
    const int lane = threadIdx.x & 63;
    const int i    = blockIdx.x * 4 + wv;

    // bitonic sort the pool across lanes (keys distinct: disjoint j; inert lanes = FFFF)
    uint32_t v = (lane < NPOOL) ? parts[(size_t)i * NPOOL + lane] : 0xFFFFFFFFu;
    #pragma unroll
    for (int kk = 2; kk <= 64; kk <<= 1) {
        #pragma unroll
        for (int jj = kk >> 1; jj > 0; jj >>= 1) {
            const uint32_t o = __shfl_xor(v, jj);
            const bool keepmin = ((lane & kk) == 0) == ((lane & jj) == 0);
            v = keepmin ? umin_(v, o) : umax_(v, o);
        }
    }
    // lanes 0..15 hold the approx top-16 ascending (self among them, typically lane 0)

    const float4 xi = *(const float4*)(X + (size_t)i * DX + lane * 4);

    float p[NCAND];
    #pragma unroll
    for (int c = 0; c < NCAND; ++c) {
        const int jc = (int)(__shfl(v, c) & 0x1FFFu);
        const float4 xj = *(const float4*)(X + (size_t)jc * DX + lane * 4);
        p[c] = fmaf(xi.x, xj.x, fmaf(xi.y, xj.y, fmaf(xi.z, xj.z, xi.w * xj.w)));
    }
    #pragma unroll
    for (int c = 0; c < NCAND; ++c) {
        p[c] += __shfl_xor(p[c], 1);
        p[c] += __shfl_xor(p[c], 2);
        p[c] += __shfl_xor(p[c], 4);
        p[c] += __shfl_xor(p[c], 8);
    }
    const int cs = lane & 15;
    float dotv = p[0];
    dotv = (cs == 1)  ? p[1]  : dotv;
    dotv = (cs == 2)  ? p[2]  : dotv;
    dotv = (cs == 3)  ? p[3]  : dotv;
    dotv = (cs == 4)  ? p[4]  : dotv;
    dotv = (cs == 5)  ? p[5]  : dotv;
    dotv = (cs == 6)  ? p[6]  : dotv;
    dotv = (cs == 7)  ? p[7]  : dotv;
    dotv = (cs == 8)  ? p[8]  : dotv;
    dotv = (cs == 9)  ? p[9]  : dotv;
    dotv = (cs == 10) ? p[10] : dotv;
    dotv = (cs == 11) ? p[11] : dotv;
    dotv = (cs == 12) ? p[12] : dotv;
    dotv = (cs == 13) ? p[13] : dotv;
    dotv = (cs == 14) ? p[14] : dotv;
    dotv = (cs == 15) ? p[15] : dotv;
    dotv += __shfl_xor(dotv, 16);
    dotv += __shfl_xor(dotv, 32);

    unsigned long long k16 = 0xFFFFFFFFFFFFFFFFull;
    const int jl = (int)(v & 0x1FFFu);
    if (lane < NCAND) {
        const float d2x = (sqX[i] + sqX[jl]) - 2.0f * dotv;
        // self: force key to jl (high-32 = 0, strictly below any d2>=0 key) so it sorts
        // first deterministically even if its d2 rounds to a tiny negative value
        k16 = (jl == i) ? (unsigned long long)(unsigned)jl
                        : (((unsigned long long)__float_as_uint(d2x) << 32) | (unsigned)jl);
    }
    #pragma unroll
    for (int kk = 2; kk <= NCAND; kk <<= 1) {
        #pragma unroll
        for (int jj = kk >> 1; jj > 0; jj >>= 1) {
            const unsigned long long o = __shfl_xor(k16, jj);
            const bool keepmin = ((lane & kk) == 0) == ((lane & jj) == 0);
            k16 = keepmin ? (k16 < o ? k16 : o) : (k16 < o ? o : k16);
        }
    }

    // lane 0 = self; lanes 1..5 hold the exact top-5 neighbors ascending
    const float d2k = __uint_as_float((uint32_t)(k16 >> 32));
    const int   jk  = (int)(k16 & 0x1FFFull);
    float lkx = 0.0f;
    if (lane >= 1 && lane <= KNN) lkx = log10f(sqrtf(fmaxf(d2k, 0.0f)) + EPS);
    const float l4x = __shfl(lkx, KNN);              // 5th neighbor = lane 5
    float sx = lkx;                                  // lanes 0,6,7 contribute 0
    sx += __shfl_xor(sx, 1);
    sx += __shfl_xor(sx, 2);
    sx += __shfl_xor(sx, 4);

    // z-distances, coalesced: 1 dim/lane; 5 neighbor rows read by the whole wave
    const float zi = Z[(size_t)i * DZ + lane];
    float zsum = 0.0f, l4z = 0.0f;
    #pragma unroll
    for (int k = 0; k < KNN; ++k) {
        const int jz = __shfl(jk, k + 1);            // neighbors at lanes 1..5
        const float zj = Z[(size_t)jz * DZ + lane];
        const float d = zi - zj;
        float s = d * d;
        s += __shfl_xor(s, 1);
        s += __shfl_xor(s, 2);
        s += __shfl_xor(s, 4);
        s += __shfl_xor(s, 8);
        s += __shfl_xor(s, 16);
        s += __shfl_xor(s, 32);
        const float lk = log10f(sqrtf(fmaxf(s, 0.0f)) + EPS);
        zsum += lk;
        if (k == KNN - 1) l4z = lk;     // compile-time branch (unrolled)
    }

    if (lane == 0) {
        const float lx = -(__shfl(sx, 0) - (float)KNN * l4x);
        const float lz = -(zsum - (float)KNN * l4z);
        const float diff = lx - lz;
        wsum[wv] = diff * diff * (1.0f / ((float)NR * KNN * 10.0f));
    }
    __syncthreads();
    if (threadIdx.x == 0)
        atomicAdd(out, wsum[0] + wsum[1] + wsum[2] + wsum[3]);
}

// ---------------------------------------------------------------- launch
extern "C" void kernel_launch(void* const* d_in, const int* in_sizes, int n_in,
                              void* d_out, int out_size, void* d_ws, size_t ws_size,
                              hipStream_t stream) {
    const float* X = (const float*)d_in[0];
    const float* Z = (const float*)d_in[1];
    float* out = (float*)d_out;

    char* ws = (char*)d_ws;
    float*     sqX      = (float*)ws;                         // 32 KB
    uint32_t*  partials = (uint32_t*)(ws + 32768);            // 8192*48*4 = 1.57 MB
    uint8_t*   Xq       = (uint8_t*)(ws + 32768 + 2097152);   // 2 MB fp8

    split_k<<<NR / 4, 256, 0, stream>>>(X, Xq, sqX, out);
    mfma_topk_k<<<(NR / RBLK) * NSPLIT, 256, 0, stream>>>(Xq, sqX, partials);
    finalize_k<<<NR / 4, 256, 0, stream>>>(partials, X, Z, sqX, out);
}